// Round 10
// baseline (688.698 us; speedup 1.0000x reference)
//
#include <hip/hip_runtime.h>

typedef _Float16 half8 __attribute__((ext_vector_type(8)));
typedef _Float16 h4 __attribute__((ext_vector_type(4)));
typedef _Float16 h2 __attribute__((ext_vector_type(2)));
typedef float f32x4 __attribute__((ext_vector_type(4)));

__device__ __forceinline__ unsigned fkey(float f) {
  unsigned u = __float_as_uint(f);
  return (u & 0x80000000u) ? ~u : (u | 0x80000000u);
}
__device__ __forceinline__ float funkey(unsigned k) {
  unsigned u = (k & 0x80000000u) ? (k ^ 0x80000000u) : ~k;
  return __uint_as_float(u);
}

__device__ __forceinline__ half8 cvt8(float4 a, float4 b) {
  half8 o;
  o[0] = (_Float16)a.x; o[1] = (_Float16)a.y; o[2] = (_Float16)a.z; o[3] = (_Float16)a.w;
  o[4] = (_Float16)b.x; o[5] = (_Float16)b.y; o[6] = (_Float16)b.z; o[7] = (_Float16)b.w;
  return o;
}

// ---------------- weight convert: fp32 KxNC -> f16 transposed NC x Kpad ----------------
struct WD { const float* src; _Float16* dst; int K, NC, Kpad, base; };
struct WDs { WD d[10]; int total; };

__global__ __launch_bounds__(256) void k_wconv(WDs w) {
  int idx = blockIdx.x * 256 + threadIdx.x;
  if (idx >= w.total) return;
#pragma unroll
  for (int i = 0; i < 10; ++i) {
    int rel = idx - w.d[i].base;
    int sz = w.d[i].NC * w.d[i].Kpad;
    if (rel >= 0 && rel < sz) {
      int n = rel / w.d[i].Kpad;
      int k = rel - n * w.d[i].Kpad;
      w.d[i].dst[rel] = (k < w.d[i].K) ? (_Float16)w.d[i].src[(size_t)k * w.d[i].NC + n]
                                       : (_Float16)0.f;
      return;
    }
  }
}

// encode weight, table-decomposed layout: W'[n][k], k<139 -> lin_w[k][n],
// 139<=k<157 -> lin_w[k+36][n] (cfg rows 175..192), 157..159 zero pad. NC=128, Kpad=160.
__global__ __launch_bounds__(256) void k_wenc2(const float* __restrict__ lin_w,
                                               _Float16* __restrict__ dst) {
  int idx = blockIdx.x * 256 + threadIdx.x;
  if (idx >= 128 * 160) return;
  int n = idx / 160, k = idx - n * 160;
  float v = (k < 139) ? lin_w[(size_t)k * 128 + n]
                      : ((k < 157) ? lin_w[(size_t)(k + 36) * 128 + n] : 0.f);
  dst[idx] = (_Float16)v;
}

// Precompute per-opcode / per-type output-row contributions (linearity of matmul):
// OPT[o][n] = sum_k op_emb[o][k] * lin_w[143+k][n]          (120 x 128, fp32)
// TYTb[t][n] = lin_b[n] + sum_k type_emb[t][k] * lin_w[139+k][n]  (8 x 128, fp32)
__global__ __launch_bounds__(256) void k_tab(const float* __restrict__ lin_w,
                                             const float* __restrict__ lin_b,
                                             const float* __restrict__ op_emb,
                                             const float* __restrict__ type_emb,
                                             float* __restrict__ OPT,
                                             float* __restrict__ TYTb) {
  int idx = blockIdx.x * 256 + threadIdx.x;
  if (idx < 120 * 128) {
    int o = idx >> 7, n = idx & 127;
    float s = 0.f;
#pragma unroll
    for (int k = 0; k < 32; ++k) s += op_emb[o * 32 + k] * lin_w[(size_t)(143 + k) * 128 + n];
    OPT[idx] = s;
  } else if (idx < 120 * 128 + 8 * 128) {
    int rel = idx - 120 * 128;
    int t = rel >> 7, n = rel & 127;
    float s = lin_b[n];
#pragma unroll
    for (int k = 0; k < 4; ++k) s += type_emb[t * 4 + k] * lin_w[(size_t)(139 + k) * 128 + n];
    TYTb[rel] = s;
  }
}

// ---------------- CSR build ----------------
__global__ __launch_bounds__(256) void k_count(const int* __restrict__ dst,
                                               int* __restrict__ counts, int E) {
  int e = blockIdx.x * 256 + threadIdx.x;
  if (e < E) atomicAdd(&counts[dst[e]], 1);
}

__global__ __launch_bounds__(256) void k_scan1(const int* __restrict__ counts,
                                               int* __restrict__ offsets,
                                               int* __restrict__ blockSums, int N) {
  __shared__ int sm[256];
  int tid = threadIdx.x;
  int gid = blockIdx.x * 256 + tid;
  int v = (gid < N) ? counts[gid] : 0;
  sm[tid] = v;
  __syncthreads();
  for (int off = 1; off < 256; off <<= 1) {
    int t = (tid >= off) ? sm[tid - off] : 0;
    __syncthreads();
    sm[tid] += t;
    __syncthreads();
  }
  if (gid < N) offsets[gid] = sm[tid] - v;
  if (tid == 255) blockSums[blockIdx.x] = sm[255];
}

__global__ __launch_bounds__(1024) void k_scan2(int* __restrict__ blockSums, int NB) {
  __shared__ int sm[1024];
  int tid = threadIdx.x;
  int v = (tid < NB) ? blockSums[tid] : 0;
  sm[tid] = v;
  __syncthreads();
  for (int off = 1; off < 1024; off <<= 1) {
    int t = (tid >= off) ? sm[tid - off] : 0;
    __syncthreads();
    sm[tid] += t;
    __syncthreads();
  }
  if (tid < NB) blockSums[tid] = sm[tid] - v;
}

__global__ __launch_bounds__(256) void k_scan3(const int* __restrict__ counts,
                                               int* __restrict__ offsets,
                                               const int* __restrict__ blockSums,
                                               int* __restrict__ fillpos,
                                               float* __restrict__ deginv, int N, int E) {
  int gid = blockIdx.x * 256 + threadIdx.x;
  if (gid < N) {
    int off = offsets[gid] + blockSums[gid >> 8];
    offsets[gid] = off;
    fillpos[gid] = off;
    deginv[gid] = 1.f / fmaxf((float)counts[gid], 1.f);
  }
  if (gid == 0) offsets[N] = E;
}

__global__ __launch_bounds__(256) void k_fill(const int* __restrict__ src,
                                              const int* __restrict__ dst,
                                              int* __restrict__ fillpos,
                                              int* __restrict__ esrc, int E) {
  int e = blockIdx.x * 256 + threadIdx.x;
  if (e < E) {
    int p = atomicAdd(&fillpos[dst[e]], 1);
    esrc[p] = src[e];
  }
}

// ---------------- fused encode, table-decomposed ----------------
// x = relu( [nf(139) | cfg(18)] @ W' + OPT[opcode] + TYTb[type] )   (K=160 incl pad)
// The embedding gathers are gone from the K-loop (moved to precomputed fp32 tables,
// loaded as the accumulator INIT — 64 L1-hot 4B loads, coalesced per 16-lane group,
// hidden under the GEMM). A-loads are pure dense float4/float2 streams; the single
// 4-way quad branch (k=4 tail) has no dependent chains. 5 k-steps (was 7).
__global__ __launch_bounds__(256) void k_mmF(
    const float* __restrict__ node_feat, const float* __restrict__ cfgf,
    const int* __restrict__ opcode,
    const float* __restrict__ OPT, const float* __restrict__ TYTb,
    const _Float16* __restrict__ W0, _Float16* __restrict__ Out, int N) {
  constexpr int NC = 128, NT = NC / 16, KP = 160;

  const int lane = threadIdx.x & 63, wave = threadIdx.x >> 6;
  const int quad = lane >> 4, l15 = lane & 15;
  const int r0 = blockIdx.x * 64 + wave * 16;

  // ---- accumulator init from tables (rows rw_j = r0+quad*4+j, col t*16+l15) ----
  int opc[4], ty[4];
#pragma unroll
  for (int j = 0; j < 4; ++j) {
    int rw = min(r0 + quad * 4 + j, N - 1);
    opc[j] = opcode[rw];
    ty[j] = min(max((int)node_feat[(size_t)rw * 140 + 139], 0), 7);
  }
  f32x4 acc[NT];
#pragma unroll
  for (int t = 0; t < NT; ++t) {
#pragma unroll
    for (int j = 0; j < 4; ++j)
      acc[t][j] = OPT[opc[j] * 128 + t * 16 + l15] + TYTb[ty[j] * 128 + t * 16 + l15];
  }

  // ---- A fragments: dense streaming loads (virtual cols: 0..138 nf | 139..156 cfg) --
  const int rA = min(r0 + l15, N - 1);
  const float* fr = node_feat + (size_t)rA * 140;
  const float* cg = cfgf + (size_t)rA * 18;
  half8 A[5];
#pragma unroll
  for (int k = 0; k < 4; ++k) {
    float4 a = *(const float4*)(fr + quad * 8 + k * 32);
    float4 b = *(const float4*)(fr + quad * 8 + k * 32 + 4);
    A[k] = cvt8(a, b);
  }
  if (quad == 0) {  // cols 128..135
    A[4] = cvt8(*(const float4*)(fr + 128), *(const float4*)(fr + 132));
  } else if (quad == 1) {  // cols 136..143 = nf136-138 | cfg0-4
    float4 a = *(const float4*)(fr + 136);
    float2 c0 = *(const float2*)(cg + 0), c1 = *(const float2*)(cg + 2),
           c2 = *(const float2*)(cg + 4);
    A[4][0] = (_Float16)a.x;  A[4][1] = (_Float16)a.y;  A[4][2] = (_Float16)a.z;
    A[4][3] = (_Float16)c0.x; A[4][4] = (_Float16)c0.y; A[4][5] = (_Float16)c1.x;
    A[4][6] = (_Float16)c1.y; A[4][7] = (_Float16)c2.x;
  } else if (quad == 2) {  // cols 144..151 = cfg5..12
    float2 c0 = *(const float2*)(cg + 4), c1 = *(const float2*)(cg + 6),
           c2 = *(const float2*)(cg + 8), c3 = *(const float2*)(cg + 10),
           c4 = *(const float2*)(cg + 12);
    A[4][0] = (_Float16)c0.y; A[4][1] = (_Float16)c1.x; A[4][2] = (_Float16)c1.y;
    A[4][3] = (_Float16)c2.x; A[4][4] = (_Float16)c2.y; A[4][5] = (_Float16)c3.x;
    A[4][6] = (_Float16)c3.y; A[4][7] = (_Float16)c4.x;
  } else {  // cols 152..159 = cfg13..17 | zeros
    float2 c0 = *(const float2*)(cg + 12), c1 = *(const float2*)(cg + 14),
           c2 = *(const float2*)(cg + 16);
    A[4][0] = (_Float16)c0.y; A[4][1] = (_Float16)c1.x; A[4][2] = (_Float16)c1.y;
    A[4][3] = (_Float16)c2.x; A[4][4] = (_Float16)c2.y;
    A[4][5] = (_Float16)0.f;  A[4][6] = (_Float16)0.f;  A[4][7] = (_Float16)0.f;
  }

  // ---- GEMM: 5 k-steps x 8 col-tiles, B direct from global (40 KB, L1/L2-hot) ----
  const _Float16* Wb = W0 + (size_t)l15 * KP + quad * 8;
#pragma unroll
  for (int k = 0; k < 5; ++k) {
#pragma unroll
    for (int t = 0; t < NT; ++t) {
      half8 b = *(const half8*)(Wb + (size_t)t * 16 * KP + k * 32);
      acc[t] = __builtin_amdgcn_mfma_f32_16x16x32_f16(A[k], b, acc[t], 0, 0, 0);
    }
  }

  // ---- epilogue: relu (bias folded into TYTb) + store ----
#pragma unroll
  for (int t = 0; t < NT; ++t) {
    acc[t][0] = fmaxf(acc[t][0], 0.f);
    acc[t][1] = fmaxf(acc[t][1], 0.f);
    acc[t][2] = fmaxf(acc[t][2], 0.f);
    acc[t][3] = fmaxf(acc[t][3], 0.f);
  }
#pragma unroll
  for (int j = 0; j < 4; ++j) {
    int rw = r0 + quad * 4 + j;
    if (rw < N) {
#pragma unroll
      for (int t = 0; t < NT; ++t)
        Out[(size_t)rw * NC + t * 16 + l15] = (_Float16)acc[t][j];
    }
  }
}

// ---------------- MFMA GEMM, B staged in LDS ----------------
// Out[r,:] = epi( A0[r]@W0 (+ A1[r]@W1) + bias ), A f16 row-major pitch K, W f16
// transposed (NC x K). MODE 0 = relu, 1 = row L2-normalize.
// 256 thr = 4 waves; 64 rows/wave (4 row-tiles), 256 rows/block.
template <int K0, int K1, int NC, int MODE>
__global__ __launch_bounds__(256) void k_mm(
    const _Float16* __restrict__ A0, const _Float16* __restrict__ W0,
    const _Float16* __restrict__ A1, const _Float16* __restrict__ W1,
    const float* __restrict__ bias, _Float16* __restrict__ Out, int N) {
  constexpr int NT = NC / 16;  // col tiles
  constexpr int RT = 4;        // row tiles per wave
  constexpr int KP0 = K0 + 8;  // padded LDS pitch (f16)
  constexpr int KP1 = K1 + 8;
  __shared__ _Float16 sB0[NC * KP0];
  __shared__ _Float16 sB1[(K1 > 0) ? (NC * KP1) : 8];

  for (int idx = threadIdx.x; idx < NC * (K0 / 8); idx += 256) {
    int nn = idx / (K0 / 8), k8 = idx - nn * (K0 / 8);
    *(half8*)(sB0 + nn * KP0 + k8 * 8) = *(const half8*)(W0 + (size_t)nn * K0 + k8 * 8);
  }
  if constexpr (K1 > 0) {
    for (int idx = threadIdx.x; idx < NC * (K1 / 8); idx += 256) {
      int nn = idx / (K1 / 8), k8 = idx - nn * (K1 / 8);
      *(half8*)(sB1 + nn * KP1 + k8 * 8) = *(const half8*)(W1 + (size_t)nn * K1 + k8 * 8);
    }
  }
  __syncthreads();

  const int lane = threadIdx.x & 63, wave = threadIdx.x >> 6;
  const int quad = lane >> 4, l15 = lane & 15;
  const int r0 = blockIdx.x * 256 + wave * 64;

  f32x4 acc[RT][NT];
#pragma unroll
  for (int rt = 0; rt < RT; ++rt)
#pragma unroll
    for (int t = 0; t < NT; ++t) acc[rt][t] = (f32x4)0.f;

  {
    const _Float16* ap = A0 + (size_t)(r0 + l15) * K0 + quad * 8;
#pragma unroll
    for (int k = 0; k < K0; k += 32) {
      half8 a[RT];
#pragma unroll
      for (int rt = 0; rt < RT; ++rt) a[rt] = *(const half8*)(ap + (size_t)rt * 16 * K0 + k);
#pragma unroll
      for (int t = 0; t < NT; ++t) {
        half8 b = *(const half8*)(sB0 + (t * 16 + l15) * KP0 + quad * 8 + k);
#pragma unroll
        for (int rt = 0; rt < RT; ++rt)
          acc[rt][t] = __builtin_amdgcn_mfma_f32_16x16x32_f16(a[rt], b, acc[rt][t], 0, 0, 0);
      }
    }
  }
  if constexpr (K1 > 0) {
    const _Float16* ap = A1 + (size_t)(r0 + l15) * K1 + quad * 8;
#pragma unroll
    for (int k = 0; k < K1; k += 32) {
      half8 a[RT];
#pragma unroll
      for (int rt = 0; rt < RT; ++rt) a[rt] = *(const half8*)(ap + (size_t)rt * 16 * K1 + k);
#pragma unroll
      for (int t = 0; t < NT; ++t) {
        half8 b = *(const half8*)(sB1 + (t * 16 + l15) * KP1 + quad * 8 + k);
#pragma unroll
        for (int rt = 0; rt < RT; ++rt)
          acc[rt][t] = __builtin_amdgcn_mfma_f32_16x16x32_f16(a[rt], b, acc[rt][t], 0, 0, 0);
      }
    }
  }

#pragma unroll
  for (int rt = 0; rt < RT; ++rt) {
#pragma unroll
    for (int t = 0; t < NT; ++t) {
      float bv = bias[t * 16 + l15];
      acc[rt][t][0] += bv; acc[rt][t][1] += bv;
      acc[rt][t][2] += bv; acc[rt][t][3] += bv;
    }
    if constexpr (MODE == 1) {
      f32x4 ss = (f32x4)0.f;
#pragma unroll
      for (int t = 0; t < NT; ++t) ss += acc[rt][t] * acc[rt][t];
#pragma unroll
      for (int j = 0; j < 4; ++j) {
        float s = ss[j];
        s += __shfl_xor(s, 1);
        s += __shfl_xor(s, 2);
        s += __shfl_xor(s, 4);
        s += __shfl_xor(s, 8);
        float sc = 1.f / fmaxf(sqrtf(s), 1e-12f);
#pragma unroll
        for (int t = 0; t < NT; ++t) acc[rt][t][j] *= sc;
      }
    } else {
#pragma unroll
      for (int t = 0; t < NT; ++t) {
        acc[rt][t][0] = fmaxf(acc[rt][t][0], 0.f);
        acc[rt][t][1] = fmaxf(acc[rt][t][1], 0.f);
        acc[rt][t][2] = fmaxf(acc[rt][t][2], 0.f);
        acc[rt][t][3] = fmaxf(acc[rt][t][3], 0.f);
      }
    }
#pragma unroll
    for (int j = 0; j < 4; ++j) {
      int r = r0 + rt * 16 + quad * 4 + j;
      if (r < N) {
#pragma unroll
        for (int t = 0; t < NT; ++t)
          Out[(size_t)r * NC + t * 16 + l15] = (_Float16)acc[rt][t][j];
      }
    }
  }
}

// ---------------- CSR mean aggregation (f16, fp32 acc), 8B/lane + 4x edge unroll ----
template <int NC>
__global__ __launch_bounds__(256) void k_agg(const _Float16* __restrict__ xp,
                                             const int* __restrict__ offs,
                                             const int* __restrict__ esrc,
                                             const float* __restrict__ deginv,
                                             _Float16* __restrict__ agg, int N) {
  constexpr int LPN = NC / 4;  // lanes per node, 4 f16 (8B) per lane
  int t = blockIdx.x * 256 + threadIdx.x;
  int node = t / LPN;
  int lane = t - node * LPN;
  if (node >= N) return;
  int s0 = offs[node], s1 = offs[node + 1];
  float a0 = 0.f, a1 = 0.f, a2 = 0.f, a3 = 0.f;
  for (int i = s0; i < s1; i += 4) {
    int nlast = s1 - 1;
    int e0 = esrc[i];
    int e1 = esrc[min(i + 1, nlast)];
    int e2 = esrc[min(i + 2, nlast)];
    int e3 = esrc[min(i + 3, nlast)];
    h4 v0 = ((const h4*)(xp + (size_t)e0 * NC))[lane];
    h4 v1 = ((const h4*)(xp + (size_t)e1 * NC))[lane];
    h4 v2 = ((const h4*)(xp + (size_t)e2 * NC))[lane];
    h4 v3 = ((const h4*)(xp + (size_t)e3 * NC))[lane];
    a0 += (float)v0[0]; a1 += (float)v0[1]; a2 += (float)v0[2]; a3 += (float)v0[3];
    if (i + 1 < s1) { a0 += (float)v1[0]; a1 += (float)v1[1]; a2 += (float)v1[2]; a3 += (float)v1[3]; }
    if (i + 2 < s1) { a0 += (float)v2[0]; a1 += (float)v2[1]; a2 += (float)v2[2]; a3 += (float)v2[3]; }
    if (i + 3 < s1) { a0 += (float)v3[0]; a1 += (float)v3[1]; a2 += (float)v3[2]; a3 += (float)v3[3]; }
  }
  float di = deginv[node];
  h4 o;
  o[0] = (_Float16)(a0 * di); o[1] = (_Float16)(a1 * di);
  o[2] = (_Float16)(a2 * di); o[3] = (_Float16)(a3 * di);
  ((h4*)(agg + (size_t)node * NC))[lane] = o;
}

// ---------------- pooling ----------------
__global__ __launch_bounds__(256) void k_pool1(const _Float16* __restrict__ x,
                                               const int* __restrict__ batch,
                                               unsigned* __restrict__ gkey,
                                               float* __restrict__ gsum,
                                               int* __restrict__ gcnt, int N) {
  int chunk = blockIdx.x * 4 + (threadIdx.x >> 6);
  int lane = threadIdx.x & 63;
  int n0 = chunk * 64;
  if (n0 >= N) return;
  int n1 = min(n0 + 64, N);
  float rmax = -3.4e38f, rsum = 0.f;
  int rcnt = 0, curb = batch[n0];
  for (int n = n0; n < n1; ++n) {
    int b = batch[n];
    if (b != curb) {
      atomicMax(&gkey[curb * 64 + lane], fkey(rmax));
      atomicAdd(&gsum[curb * 64 + lane], rsum);
      if (lane == 0) atomicAdd(&gcnt[curb], rcnt);
      rmax = -3.4e38f; rsum = 0.f; rcnt = 0; curb = b;
    }
    float v = (float)x[(size_t)n * 64 + lane];
    rmax = fmaxf(rmax, v);
    rsum += v;
    rcnt++;
  }
  atomicMax(&gkey[curb * 64 + lane], fkey(rmax));
  atomicAdd(&gsum[curb * 64 + lane], rsum);
  if (lane == 0) atomicAdd(&gcnt[curb], rcnt);
}

__global__ __launch_bounds__(1024) void k_pool2(const unsigned* __restrict__ gkey,
                                                const float* __restrict__ gsum,
                                                const int* __restrict__ gcnt,
                                                const float* __restrict__ post_w,
                                                const float* __restrict__ post_b,
                                                float* __restrict__ out) {
  int b = threadIdx.x >> 6, lane = threadIdx.x & 63;
  float m = funkey(gkey[b * 64 + lane]);
  float s = gsum[b * 64 + lane];
  float c = (float)gcnt[b];
  float g = m + s / fmaxf(c, 1.f);
  float ss = g * g;
#pragma unroll
  for (int off = 1; off < 64; off <<= 1) ss += __shfl_xor(ss, off);
  float gn = g / fmaxf(sqrtf(ss), 1e-30f);
  float contrib = gn * post_w[lane];
#pragma unroll
  for (int off = 1; off < 64; off <<= 1) contrib += __shfl_xor(contrib, off);
  if (lane == 0) out[b] = contrib + post_b[0];
}

extern "C" void kernel_launch(void* const* d_in, const int* in_sizes, int n_in,
                              void* d_out, int out_size, void* d_ws, size_t ws_size,
                              hipStream_t stream) {
  const float* node_feat = (const float*)d_in[0];
  const float* cfgf      = (const float*)d_in[1];
  const int*   opcode    = (const int*)d_in[2];
  const int*   eidx      = (const int*)d_in[3];
  const int*   batch     = (const int*)d_in[4];
  const float* op_emb    = (const float*)d_in[5];
  const float* type_emb  = (const float*)d_in[6];
  const float* lin_w     = (const float*)d_in[7];
  const float* lin_b     = (const float*)d_in[8];
  const float* post_w    = (const float*)d_in[9];
  const float* post_b    = (const float*)d_in[10];
  const float* wp[3] = {(const float*)d_in[11], (const float*)d_in[16], (const float*)d_in[21]};
  const float* bp[3] = {(const float*)d_in[12], (const float*)d_in[17], (const float*)d_in[22]};
  const float* wl[3] = {(const float*)d_in[13], (const float*)d_in[18], (const float*)d_in[23]};
  const float* bl[3] = {(const float*)d_in[14], (const float*)d_in[19], (const float*)d_in[24]};
  const float* wr[3] = {(const float*)d_in[15], (const float*)d_in[20], (const float*)d_in[25]};

  const int N = in_sizes[2];
  const int E = in_sizes[3] / 2;
  const int NPAD = ((N + 255) / 256) * 256;
  const int* e_src = eidx;
  const int* e_dst = eidx + E;

  char* p = (char*)d_ws;
  auto alloc = [&](size_t bytes) -> void* {
    void* r = (void*)p;
    p += (bytes + 255) & ~(size_t)255;
    return r;
  };
  _Float16* X1 = (_Float16*)alloc((size_t)NPAD * 128 * 2);
  _Float16* R2 = (_Float16*)alloc((size_t)NPAD * 128 * 2);
  _Float16* R3 = (_Float16*)alloc((size_t)NPAD * 128 * 2);
  _Float16* WT = (_Float16*)alloc(86016 * 2);
  int* counts    = (int*)alloc((size_t)N * 4);
  int* offsets   = (int*)alloc((size_t)(N + 1) * 4);
  int* fillpos   = (int*)alloc((size_t)N * 4);
  float* deginv  = (float*)alloc((size_t)N * 4);
  int* blockSums = (int*)alloc(1024 * 4);
  int* esrc      = (int*)alloc((size_t)E * 4);
  unsigned* gkey = (unsigned*)alloc(16 * 64 * 4);
  float* gsum    = (float*)alloc(16 * 64 * 4);
  int* gcnt      = (int*)alloc(16 * 4);
  float* OPT     = (float*)alloc(120 * 128 * 4);
  float* TYTb    = (float*)alloc(8 * 128 * 4);
  (void)ws_size; (void)n_in; (void)out_size;

  _Float16* WTenc = WT + 0;       // 128 x 160 (table-decomposed encode weight)
  _Float16* WTp0  = WT + 28672;   // 128 x 128
  _Float16* WTl0  = WT + 45056;   // 64 x 128
  _Float16* WTr0  = WT + 53248;   // 64 x 128
  _Float16* WTp1  = WT + 61440;   // 64 x 64
  _Float16* WTl1  = WT + 65536;
  _Float16* WTr1  = WT + 69632;
  _Float16* WTp2  = WT + 73728;
  _Float16* WTl2  = WT + 77824;
  _Float16* WTr2  = WT + 81920;

  WDs wds;
  wds.d[0] = {lin_w, WTenc, 0, 0, 1, 0};  // zero-size: encode weight built by k_wenc2
  wds.d[1] = {wp[0], WTp0, 128, 128, 128, 28672};
  wds.d[2] = {wl[0], WTl0, 128, 64, 128, 45056};
  wds.d[3] = {wr[0], WTr0, 128, 64, 128, 53248};
  wds.d[4] = {wp[1], WTp1, 64, 64, 64, 61440};
  wds.d[5] = {wl[1], WTl1, 64, 64, 64, 65536};
  wds.d[6] = {wr[1], WTr1, 64, 64, 64, 69632};
  wds.d[7] = {wp[2], WTp2, 64, 64, 64, 73728};
  wds.d[8] = {wl[2], WTl2, 64, 64, 64, 77824};
  wds.d[9] = {wr[2], WTr2, 64, 64, 64, 81920};
  wds.total = 86016;

  hipMemsetAsync(counts, 0, (size_t)N * 4, stream);
  hipMemsetAsync(gkey, 0, 16 * 64 * 4, stream);
  hipMemsetAsync(gsum, 0, 16 * 64 * 4, stream);
  hipMemsetAsync(gcnt, 0, 16 * 4, stream);
  // Zero the never-stored tail rows [N, NPAD) of the activation buffers so every
  // byte any kernel reads is written in-launch -> output is call-invariant under
  // graph replay / workspace re-poisoning (k_mm A-loads cover NPAD rows; stores
  // are guarded r < N). 48 KiB each — negligible.
  if (NPAD > N) {
    const size_t tail = (size_t)(NPAD - N) * 128 * 2;
    hipMemsetAsync(X1 + (size_t)N * 128, 0, tail, stream);
    hipMemsetAsync(R2 + (size_t)N * 128, 0, tail, stream);
    hipMemsetAsync(R3 + (size_t)N * 128, 0, tail, stream);
  }

  const int nbE = (E + 255) / 256;
  const int nbN = (N + 255) / 256;
  const int nbMM = NPAD / 256;
  const int nbMMF = NPAD / 64;
  const int nbA128 = ((size_t)N * 32 + 255) / 256;
  const int nbA64  = ((size_t)N * 16 + 255) / 256;
  const int nbP = ((N + 63) / 64 + 3) / 4;

  k_wconv<<<(86016 + 255) / 256, 256, 0, stream>>>(wds);
  k_wenc2<<<(128 * 160 + 255) / 256, 256, 0, stream>>>(lin_w, WTenc);
  k_tab<<<(120 * 128 + 8 * 128 + 255) / 256, 256, 0, stream>>>(lin_w, lin_b, op_emb,
                                                               type_emb, OPT, TYTb);
  k_count<<<nbE, 256, 0, stream>>>(e_dst, counts, E);
  k_scan1<<<nbN, 256, 0, stream>>>(counts, offsets, blockSums, N);
  k_scan2<<<1, 1024, 0, stream>>>(blockSums, nbN);
  k_scan3<<<nbN, 256, 0, stream>>>(counts, offsets, blockSums, fillpos, deginv, N, E);
  k_fill<<<nbE, 256, 0, stream>>>(e_src, e_dst, fillpos, esrc, E);

  // fused encode (table-decomposed): relu([nf|cfg]@W' + OPT[op] + TYTb[ty]) -> X1
  k_mmF<<<nbMMF, 256, 0, stream>>>(node_feat, cfgf, opcode, OPT, TYTb, WTenc, X1, N);

  // ---- layer 0 ----
  k_mm<128, 0, 128, 0><<<nbMM, 256, 0, stream>>>(X1, WTp0, nullptr, nullptr, bp[0], R2, N);
  k_agg<128><<<nbA128, 256, 0, stream>>>(R2, offsets, esrc, deginv, R3, N);
  k_mm<128, 128, 64, 1><<<nbMM, 256, 0, stream>>>(R3, WTl0, X1, WTr0, bl[0], R2, N);
  // ---- layer 1 ----
  k_mm<64, 0, 64, 0><<<nbMM, 256, 0, stream>>>(R2, WTp1, nullptr, nullptr, bp[1], R3, N);
  k_agg<64><<<nbA64, 256, 0, stream>>>(R3, offsets, esrc, deginv, X1, N);
  k_mm<64, 64, 64, 1><<<nbMM, 256, 0, stream>>>(X1, WTl1, R2, WTr1, bl[1], R3, N);
  // ---- layer 2 ----
  k_mm<64, 0, 64, 0><<<nbMM, 256, 0, stream>>>(R3, WTp2, nullptr, nullptr, bp[2], X1, N);
  k_agg<64><<<nbA64, 256, 0, stream>>>(X1, offsets, esrc, deginv, R2, N);
  k_mm<64, 64, 64, 1><<<nbMM, 256, 0, stream>>>(R2, WTl2, R3, WTr2, bl[2], X1, N);

  // pooling -> out (B=16)
  k_pool1<<<nbP, 256, 0, stream>>>(X1, batch, gkey, gsum, gcnt, N);
  k_pool2<<<1, 1024, 0, stream>>>(gkey, gsum, gcnt, post_w, post_b, (float*)d_out);
}

// Round 12
// 678.605 us; speedup vs baseline: 1.0149x; 1.0149x over previous
//
#include <hip/hip_runtime.h>

typedef _Float16 half8 __attribute__((ext_vector_type(8)));
typedef _Float16 h4 __attribute__((ext_vector_type(4)));
typedef _Float16 h2 __attribute__((ext_vector_type(2)));
typedef float f32x4 __attribute__((ext_vector_type(4)));

__device__ __forceinline__ unsigned fkey(float f) {
  unsigned u = __float_as_uint(f);
  return (u & 0x80000000u) ? ~u : (u | 0x80000000u);
}
__device__ __forceinline__ float funkey(unsigned k) {
  unsigned u = (k & 0x80000000u) ? (k ^ 0x80000000u) : ~k;
  return __uint_as_float(u);
}

__device__ __forceinline__ half8 cvt8(float4 a, float4 b) {
  half8 o;
  o[0] = (_Float16)a.x; o[1] = (_Float16)a.y; o[2] = (_Float16)a.z; o[3] = (_Float16)a.w;
  o[4] = (_Float16)b.x; o[5] = (_Float16)b.y; o[6] = (_Float16)b.z; o[7] = (_Float16)b.w;
  return o;
}

// ---------------- weight convert: fp32 KxNC -> f16 transposed NC x Kpad ----------------
struct WD { const float* src; _Float16* dst; int K, NC, Kpad, base; };
struct WDs { WD d[10]; int total; };

__global__ __launch_bounds__(256) void k_wconv(WDs w) {
  int idx = blockIdx.x * 256 + threadIdx.x;
  if (idx >= w.total) return;
#pragma unroll
  for (int i = 0; i < 10; ++i) {
    int rel = idx - w.d[i].base;
    int sz = w.d[i].NC * w.d[i].Kpad;
    if (rel >= 0 && rel < sz) {
      int n = rel / w.d[i].Kpad;
      int k = rel - n * w.d[i].Kpad;
      w.d[i].dst[rel] = (k < w.d[i].K) ? (_Float16)w.d[i].src[(size_t)k * w.d[i].NC + n]
                                       : (_Float16)0.f;
      return;
    }
  }
}

// encode weight, table-decomposed layout: W'[n][k], k<139 -> lin_w[k][n],
// 139<=k<157 -> lin_w[k+36][n] (cfg rows 175..192), 157..159 zero pad. NC=128, Kpad=160.
__global__ __launch_bounds__(256) void k_wenc2(const float* __restrict__ lin_w,
                                               _Float16* __restrict__ dst) {
  int idx = blockIdx.x * 256 + threadIdx.x;
  if (idx >= 128 * 160) return;
  int n = idx / 160, k = idx - n * 160;
  float v = (k < 139) ? lin_w[(size_t)k * 128 + n]
                      : ((k < 157) ? lin_w[(size_t)(k + 36) * 128 + n] : 0.f);
  dst[idx] = (_Float16)v;
}

// Precompute per-opcode / per-type output-row contributions (linearity of matmul):
// OPT[o][n] = sum_k op_emb[o][k] * lin_w[143+k][n]          (120 x 128, fp32)
// TYTb[t][n] = lin_b[n] + sum_k type_emb[t][k] * lin_w[139+k][n]  (8 x 128, fp32)
__global__ __launch_bounds__(256) void k_tab(const float* __restrict__ lin_w,
                                             const float* __restrict__ lin_b,
                                             const float* __restrict__ op_emb,
                                             const float* __restrict__ type_emb,
                                             float* __restrict__ OPT,
                                             float* __restrict__ TYTb) {
  int idx = blockIdx.x * 256 + threadIdx.x;
  if (idx < 120 * 128) {
    int o = idx >> 7, n = idx & 127;
    float s = 0.f;
#pragma unroll
    for (int k = 0; k < 32; ++k) s += op_emb[o * 32 + k] * lin_w[(size_t)(143 + k) * 128 + n];
    OPT[idx] = s;
  } else if (idx < 120 * 128 + 8 * 128) {
    int rel = idx - 120 * 128;
    int t = rel >> 7, n = rel & 127;
    float s = lin_b[n];
#pragma unroll
    for (int k = 0; k < 4; ++k) s += type_emb[t * 4 + k] * lin_w[(size_t)(139 + k) * 128 + n];
    TYTb[rel] = s;
  }
}

// ---------------- CSR build ----------------
__global__ __launch_bounds__(256) void k_count(const int* __restrict__ dst,
                                               int* __restrict__ counts, int E) {
  int e = blockIdx.x * 256 + threadIdx.x;
  if (e < E) atomicAdd(&counts[dst[e]], 1);
}

__global__ __launch_bounds__(256) void k_scan1(const int* __restrict__ counts,
                                               int* __restrict__ offsets,
                                               int* __restrict__ blockSums, int N) {
  __shared__ int sm[256];
  int tid = threadIdx.x;
  int gid = blockIdx.x * 256 + tid;
  int v = (gid < N) ? counts[gid] : 0;
  sm[tid] = v;
  __syncthreads();
  for (int off = 1; off < 256; off <<= 1) {
    int t = (tid >= off) ? sm[tid - off] : 0;
    __syncthreads();
    sm[tid] += t;
    __syncthreads();
  }
  if (gid < N) offsets[gid] = sm[tid] - v;
  if (tid == 255) blockSums[blockIdx.x] = sm[255];
}

__global__ __launch_bounds__(1024) void k_scan2(int* __restrict__ blockSums, int NB) {
  __shared__ int sm[1024];
  int tid = threadIdx.x;
  int v = (tid < NB) ? blockSums[tid] : 0;
  sm[tid] = v;
  __syncthreads();
  for (int off = 1; off < 1024; off <<= 1) {
    int t = (tid >= off) ? sm[tid - off] : 0;
    __syncthreads();
    sm[tid] += t;
    __syncthreads();
  }
  if (tid < NB) blockSums[tid] = sm[tid] - v;
}

__global__ __launch_bounds__(256) void k_scan3(const int* __restrict__ counts,
                                               int* __restrict__ offsets,
                                               const int* __restrict__ blockSums,
                                               int* __restrict__ fillpos,
                                               float* __restrict__ deginv, int N, int E) {
  int gid = blockIdx.x * 256 + threadIdx.x;
  if (gid < N) {
    int off = offsets[gid] + blockSums[gid >> 8];
    offsets[gid] = off;
    fillpos[gid] = off;
    deginv[gid] = 1.f / fmaxf((float)counts[gid], 1.f);
  }
  if (gid == 0) offsets[N] = E;
}

__global__ __launch_bounds__(256) void k_fill(const int* __restrict__ src,
                                              const int* __restrict__ dst,
                                              int* __restrict__ fillpos,
                                              int* __restrict__ esrc, int E) {
  int e = blockIdx.x * 256 + threadIdx.x;
  if (e < E) {
    int p = atomicAdd(&fillpos[dst[e]], 1);
    esrc[p] = src[e];
  }
}

// ---------------- fused encode, table-decomposed, all-LDS steady state ----------------
// x = relu( [nf(139)|cfg(18)] @ W' + OPT[opcode] + TYTb[type] )    (K=160 incl pad)
// The k-loop and acc-init touch ONLY LDS/registers: B (128x160 f16, pitch 168 ->
// 2-way bank aliasing = free) and the per-row table sum sT (64x128 f32, pitch 132 ->
// 2-way) are staged once per block with independent coalesced loads (~41 VMEM/thread,
// was ~157 in r10). LDS 77 KB -> 2 blocks/CU; per-wave critical path ~3K cyc.
// r11 bug fixed: acc-init row index must include wave*16 (sT rows are block-local).
__global__ __launch_bounds__(256) void k_mmF(
    const float* __restrict__ node_feat, const float* __restrict__ cfgf,
    const int* __restrict__ opcode,
    const float* __restrict__ OPT, const float* __restrict__ TYTb,
    const _Float16* __restrict__ W0, _Float16* __restrict__ Out, int N) {
  constexpr int NC = 128, NT = NC / 16;
  constexpr int BP = 168;  // sB pitch (f16)
  constexpr int TP = 132;  // sT pitch (f32)
  __shared__ _Float16 sB[128 * BP];  // 43008 B
  __shared__ float sT[64 * TP];      // 33792 B
  __shared__ int sOp[64], sTy[64];

  const int tid = threadIdx.x;
  const int base = blockIdx.x * 64;
  const int lane = tid & 63, wave = tid >> 6;
  const int quad = lane >> 4, l15 = lane & 15;
  const int r0 = base + wave * 16;

  // ---- phase 0: row meta (64 threads) ----
  if (tid < 64) {
    int rw = min(base + tid, N - 1);
    sOp[tid] = opcode[rw];
    sTy[tid] = min(max((int)node_feat[(size_t)rw * 140 + 139], 0), 7);
  }

  // ---- A fragments: dense streaming register loads (independent of phase 0) ----
  const int rA = min(r0 + l15, N - 1);
  const float* fr = node_feat + (size_t)rA * 140;
  const float* cg = cfgf + (size_t)rA * 18;
  half8 A[5];
#pragma unroll
  for (int k = 0; k < 4; ++k) {
    float4 a = *(const float4*)(fr + quad * 8 + k * 32);
    float4 b = *(const float4*)(fr + quad * 8 + k * 32 + 4);
    A[k] = cvt8(a, b);
  }
  if (quad == 0) {  // cols 128..135
    A[4] = cvt8(*(const float4*)(fr + 128), *(const float4*)(fr + 132));
  } else if (quad == 1) {  // cols 136..143 = nf136-138 | cfg0-4
    float4 a = *(const float4*)(fr + 136);
    float2 c0 = *(const float2*)(cg + 0), c1 = *(const float2*)(cg + 2),
           c2 = *(const float2*)(cg + 4);
    A[4][0] = (_Float16)a.x;  A[4][1] = (_Float16)a.y;  A[4][2] = (_Float16)a.z;
    A[4][3] = (_Float16)c0.x; A[4][4] = (_Float16)c0.y; A[4][5] = (_Float16)c1.x;
    A[4][6] = (_Float16)c1.y; A[4][7] = (_Float16)c2.x;
  } else if (quad == 2) {  // cols 144..151 = cfg5..12
    float2 c0 = *(const float2*)(cg + 4), c1 = *(const float2*)(cg + 6),
           c2 = *(const float2*)(cg + 8), c3 = *(const float2*)(cg + 10),
           c4 = *(const float2*)(cg + 12);
    A[4][0] = (_Float16)c0.y; A[4][1] = (_Float16)c1.x; A[4][2] = (_Float16)c1.y;
    A[4][3] = (_Float16)c2.x; A[4][4] = (_Float16)c2.y; A[4][5] = (_Float16)c3.x;
    A[4][6] = (_Float16)c3.y; A[4][7] = (_Float16)c4.x;
  } else {  // cols 152..159 = cfg13..17 | zeros
    float2 c0 = *(const float2*)(cg + 12), c1 = *(const float2*)(cg + 14),
           c2 = *(const float2*)(cg + 16);
    A[4][0] = (_Float16)c0.y; A[4][1] = (_Float16)c1.x; A[4][2] = (_Float16)c1.y;
    A[4][3] = (_Float16)c2.x; A[4][4] = (_Float16)c2.y;
    A[4][5] = (_Float16)0.f;  A[4][6] = (_Float16)0.f;  A[4][7] = (_Float16)0.f;
  }

  // ---- stage B (shared by block; 2560 half8 / 256 thr = 10 each) ----
  for (int i = tid; i < 2560; i += 256) {
    int n = i / 20, k8 = i - n * 20;
    *(half8*)(sB + n * BP + k8 * 8) = *(const half8*)(W0 + (size_t)n * 160 + k8 * 8);
  }
  __syncthreads();  // sOp/sTy ready

  // ---- stage table-sum sT[r][c] = OPT[opc[r]][c] + TYTb[ty[r]][c] (2048 float4) ----
  for (int i = tid; i < 2048; i += 256) {
    int r = i >> 5, c4 = i & 31;
    float4 o = *(const float4*)(OPT + (size_t)sOp[r] * 128 + c4 * 4);
    float4 t = *(const float4*)(TYTb + (size_t)sTy[r] * 128 + c4 * 4);
    float4 s;
    s.x = o.x + t.x; s.y = o.y + t.y; s.z = o.z + t.z; s.w = o.w + t.w;
    *(float4*)(sT + r * TP + c4 * 4) = s;
  }
  __syncthreads();

  // ---- acc init from sT (rows are block-local: wave*16 + quad*4 + j) ----
  f32x4 acc[NT];
#pragma unroll
  for (int t = 0; t < NT; ++t) {
#pragma unroll
    for (int j = 0; j < 4; ++j)
      acc[t][j] = sT[(wave * 16 + quad * 4 + j) * TP + t * 16 + l15];
  }

  // ---- GEMM: 5 k-steps x 8 col-tiles, all operands LDS/registers ----
#pragma unroll
  for (int k = 0; k < 5; ++k) {
#pragma unroll
    for (int t = 0; t < NT; ++t) {
      half8 b = *(const half8*)(sB + (t * 16 + l15) * BP + quad * 8 + k * 32);
      acc[t] = __builtin_amdgcn_mfma_f32_16x16x32_f16(A[k], b, acc[t], 0, 0, 0);
    }
  }

  // ---- epilogue: relu (bias folded into TYTb) + store ----
#pragma unroll
  for (int t = 0; t < NT; ++t) {
    acc[t][0] = fmaxf(acc[t][0], 0.f);
    acc[t][1] = fmaxf(acc[t][1], 0.f);
    acc[t][2] = fmaxf(acc[t][2], 0.f);
    acc[t][3] = fmaxf(acc[t][3], 0.f);
  }
#pragma unroll
  for (int j = 0; j < 4; ++j) {
    int rw = r0 + quad * 4 + j;
    if (rw < N) {
#pragma unroll
      for (int t = 0; t < NT; ++t)
        Out[(size_t)rw * NC + t * 16 + l15] = (_Float16)acc[t][j];
    }
  }
}

// ---------------- MFMA GEMM, B staged in LDS ----------------
// Out[r,:] = epi( A0[r]@W0 (+ A1[r]@W1) + bias ), A f16 row-major pitch K, W f16
// transposed (NC x K). MODE 0 = relu, 1 = row L2-normalize.
// 256 thr = 4 waves; 64 rows/wave (4 row-tiles), 256 rows/block.
template <int K0, int K1, int NC, int MODE>
__global__ __launch_bounds__(256) void k_mm(
    const _Float16* __restrict__ A0, const _Float16* __restrict__ W0,
    const _Float16* __restrict__ A1, const _Float16* __restrict__ W1,
    const float* __restrict__ bias, _Float16* __restrict__ Out, int N) {
  constexpr int NT = NC / 16;  // col tiles
  constexpr int RT = 4;        // row tiles per wave
  constexpr int KP0 = K0 + 8;  // padded LDS pitch (f16)
  constexpr int KP1 = K1 + 8;
  __shared__ _Float16 sB0[NC * KP0];
  __shared__ _Float16 sB1[(K1 > 0) ? (NC * KP1) : 8];

  for (int idx = threadIdx.x; idx < NC * (K0 / 8); idx += 256) {
    int nn = idx / (K0 / 8), k8 = idx - nn * (K0 / 8);
    *(half8*)(sB0 + nn * KP0 + k8 * 8) = *(const half8*)(W0 + (size_t)nn * K0 + k8 * 8);
  }
  if constexpr (K1 > 0) {
    for (int idx = threadIdx.x; idx < NC * (K1 / 8); idx += 256) {
      int nn = idx / (K1 / 8), k8 = idx - nn * (K1 / 8);
      *(half8*)(sB1 + nn * KP1 + k8 * 8) = *(const half8*)(W1 + (size_t)nn * K1 + k8 * 8);
    }
  }
  __syncthreads();

  const int lane = threadIdx.x & 63, wave = threadIdx.x >> 6;
  const int quad = lane >> 4, l15 = lane & 15;
  const int r0 = blockIdx.x * 256 + wave * 64;

  f32x4 acc[RT][NT];
#pragma unroll
  for (int rt = 0; rt < RT; ++rt)
#pragma unroll
    for (int t = 0; t < NT; ++t) acc[rt][t] = (f32x4)0.f;

  {
    const _Float16* ap = A0 + (size_t)(r0 + l15) * K0 + quad * 8;
#pragma unroll
    for (int k = 0; k < K0; k += 32) {
      half8 a[RT];
#pragma unroll
      for (int rt = 0; rt < RT; ++rt) a[rt] = *(const half8*)(ap + (size_t)rt * 16 * K0 + k);
#pragma unroll
      for (int t = 0; t < NT; ++t) {
        half8 b = *(const half8*)(sB0 + (t * 16 + l15) * KP0 + quad * 8 + k);
#pragma unroll
        for (int rt = 0; rt < RT; ++rt)
          acc[rt][t] = __builtin_amdgcn_mfma_f32_16x16x32_f16(a[rt], b, acc[rt][t], 0, 0, 0);
      }
    }
  }
  if constexpr (K1 > 0) {
    const _Float16* ap = A1 + (size_t)(r0 + l15) * K1 + quad * 8;
#pragma unroll
    for (int k = 0; k < K1; k += 32) {
      half8 a[RT];
#pragma unroll
      for (int rt = 0; rt < RT; ++rt) a[rt] = *(const half8*)(ap + (size_t)rt * 16 * K1 + k);
#pragma unroll
      for (int t = 0; t < NT; ++t) {
        half8 b = *(const half8*)(sB1 + (t * 16 + l15) * KP1 + quad * 8 + k);
#pragma unroll
        for (int rt = 0; rt < RT; ++rt)
          acc[rt][t] = __builtin_amdgcn_mfma_f32_16x16x32_f16(a[rt], b, acc[rt][t], 0, 0, 0);
      }
    }
  }

#pragma unroll
  for (int rt = 0; rt < RT; ++rt) {
#pragma unroll
    for (int t = 0; t < NT; ++t) {
      float bv = bias[t * 16 + l15];
      acc[rt][t][0] += bv; acc[rt][t][1] += bv;
      acc[rt][t][2] += bv; acc[rt][t][3] += bv;
    }
    if constexpr (MODE == 1) {
      f32x4 ss = (f32x4)0.f;
#pragma unroll
      for (int t = 0; t < NT; ++t) ss += acc[rt][t] * acc[rt][t];
#pragma unroll
      for (int j = 0; j < 4; ++j) {
        float s = ss[j];
        s += __shfl_xor(s, 1);
        s += __shfl_xor(s, 2);
        s += __shfl_xor(s, 4);
        s += __shfl_xor(s, 8);
        float sc = 1.f / fmaxf(sqrtf(s), 1e-12f);
#pragma unroll
        for (int t = 0; t < NT; ++t) acc[rt][t][j] *= sc;
      }
    } else {
#pragma unroll
      for (int t = 0; t < NT; ++t) {
        acc[rt][t][0] = fmaxf(acc[rt][t][0], 0.f);
        acc[rt][t][1] = fmaxf(acc[rt][t][1], 0.f);
        acc[rt][t][2] = fmaxf(acc[rt][t][2], 0.f);
        acc[rt][t][3] = fmaxf(acc[rt][t][3], 0.f);
      }
    }
#pragma unroll
    for (int j = 0; j < 4; ++j) {
      int r = r0 + rt * 16 + quad * 4 + j;
      if (r < N) {
#pragma unroll
        for (int t = 0; t < NT; ++t)
          Out[(size_t)r * NC + t * 16 + l15] = (_Float16)acc[rt][t][j];
      }
    }
  }
}

// ---------------- CSR mean aggregation (f16, fp32 acc), 8B/lane + 4x edge unroll ----
template <int NC>
__global__ __launch_bounds__(256) void k_agg(const _Float16* __restrict__ xp,
                                             const int* __restrict__ offs,
                                             const int* __restrict__ esrc,
                                             const float* __restrict__ deginv,
                                             _Float16* __restrict__ agg, int N) {
  constexpr int LPN = NC / 4;  // lanes per node, 4 f16 (8B) per lane
  int t = blockIdx.x * 256 + threadIdx.x;
  int node = t / LPN;
  int lane = t - node * LPN;
  if (node >= N) return;
  int s0 = offs[node], s1 = offs[node + 1];
  float a0 = 0.f, a1 = 0.f, a2 = 0.f, a3 = 0.f;
  for (int i = s0; i < s1; i += 4) {
    int nlast = s1 - 1;
    int e0 = esrc[i];
    int e1 = esrc[min(i + 1, nlast)];
    int e2 = esrc[min(i + 2, nlast)];
    int e3 = esrc[min(i + 3, nlast)];
    h4 v0 = ((const h4*)(xp + (size_t)e0 * NC))[lane];
    h4 v1 = ((const h4*)(xp + (size_t)e1 * NC))[lane];
    h4 v2 = ((const h4*)(xp + (size_t)e2 * NC))[lane];
    h4 v3 = ((const h4*)(xp + (size_t)e3 * NC))[lane];
    a0 += (float)v0[0]; a1 += (float)v0[1]; a2 += (float)v0[2]; a3 += (float)v0[3];
    if (i + 1 < s1) { a0 += (float)v1[0]; a1 += (float)v1[1]; a2 += (float)v1[2]; a3 += (float)v1[3]; }
    if (i + 2 < s1) { a0 += (float)v2[0]; a1 += (float)v2[1]; a2 += (float)v2[2]; a3 += (float)v2[3]; }
    if (i + 3 < s1) { a0 += (float)v3[0]; a1 += (float)v3[1]; a2 += (float)v3[2]; a3 += (float)v3[3]; }
  }
  float di = deginv[node];
  h4 o;
  o[0] = (_Float16)(a0 * di); o[1] = (_Float16)(a1 * di);
  o[2] = (_Float16)(a2 * di); o[3] = (_Float16)(a3 * di);
  ((h4*)(agg + (size_t)node * NC))[lane] = o;
}

// ---------------- pooling ----------------
__global__ __launch_bounds__(256) void k_pool1(const _Float16* __restrict__ x,
                                               const int* __restrict__ batch,
                                               unsigned* __restrict__ gkey,
                                               float* __restrict__ gsum,
                                               int* __restrict__ gcnt, int N) {
  int chunk = blockIdx.x * 4 + (threadIdx.x >> 6);
  int lane = threadIdx.x & 63;
  int n0 = chunk * 64;
  if (n0 >= N) return;
  int n1 = min(n0 + 64, N);
  float rmax = -3.4e38f, rsum = 0.f;
  int rcnt = 0, curb = batch[n0];
  for (int n = n0; n < n1; ++n) {
    int b = batch[n];
    if (b != curb) {
      atomicMax(&gkey[curb * 64 + lane], fkey(rmax));
      atomicAdd(&gsum[curb * 64 + lane], rsum);
      if (lane == 0) atomicAdd(&gcnt[curb], rcnt);
      rmax = -3.4e38f; rsum = 0.f; rcnt = 0; curb = b;
    }
    float v = (float)x[(size_t)n * 64 + lane];
    rmax = fmaxf(rmax, v);
    rsum += v;
    rcnt++;
  }
  atomicMax(&gkey[curb * 64 + lane], fkey(rmax));
  atomicAdd(&gsum[curb * 64 + lane], rsum);
  if (lane == 0) atomicAdd(&gcnt[curb], rcnt);
}

__global__ __launch_bounds__(1024) void k_pool2(const unsigned* __restrict__ gkey,
                                                const float* __restrict__ gsum,
                                                const int* __restrict__ gcnt,
                                                const float* __restrict__ post_w,
                                                const float* __restrict__ post_b,
                                                float* __restrict__ out) {
  int b = threadIdx.x >> 6, lane = threadIdx.x & 63;
  float m = funkey(gkey[b * 64 + lane]);
  float s = gsum[b * 64 + lane];
  float c = (float)gcnt[b];
  float g = m + s / fmaxf(c, 1.f);
  float ss = g * g;
#pragma unroll
  for (int off = 1; off < 64; off <<= 1) ss += __shfl_xor(ss, off);
  float gn = g / fmaxf(sqrtf(ss), 1e-30f);
  float contrib = gn * post_w[lane];
#pragma unroll
  for (int off = 1; off < 64; off <<= 1) contrib += __shfl_xor(contrib, off);
  if (lane == 0) out[b] = contrib + post_b[0];
}

extern "C" void kernel_launch(void* const* d_in, const int* in_sizes, int n_in,
                              void* d_out, int out_size, void* d_ws, size_t ws_size,
                              hipStream_t stream) {
  const float* node_feat = (const float*)d_in[0];
  const float* cfgf      = (const float*)d_in[1];
  const int*   opcode    = (const int*)d_in[2];
  const int*   eidx      = (const int*)d_in[3];
  const int*   batch     = (const int*)d_in[4];
  const float* op_emb    = (const float*)d_in[5];
  const float* type_emb  = (const float*)d_in[6];
  const float* lin_w     = (const float*)d_in[7];
  const float* lin_b     = (const float*)d_in[8];
  const float* post_w    = (const float*)d_in[9];
  const float* post_b    = (const float*)d_in[10];
  const float* wp[3] = {(const float*)d_in[11], (const float*)d_in[16], (const float*)d_in[21]};
  const float* bp[3] = {(const float*)d_in[12], (const float*)d_in[17], (const float*)d_in[22]};
  const float* wl[3] = {(const float*)d_in[13], (const float*)d_in[18], (const float*)d_in[23]};
  const float* bl[3] = {(const float*)d_in[14], (const float*)d_in[19], (const float*)d_in[24]};
  const float* wr[3] = {(const float*)d_in[15], (const float*)d_in[20], (const float*)d_in[25]};

  const int N = in_sizes[2];
  const int E = in_sizes[3] / 2;
  const int NPAD = ((N + 255) / 256) * 256;
  const int* e_src = eidx;
  const int* e_dst = eidx + E;

  char* p = (char*)d_ws;
  auto alloc = [&](size_t bytes) -> void* {
    void* r = (void*)p;
    p += (bytes + 255) & ~(size_t)255;
    return r;
  };
  _Float16* X1 = (_Float16*)alloc((size_t)NPAD * 128 * 2);
  _Float16* R2 = (_Float16*)alloc((size_t)NPAD * 128 * 2);
  _Float16* R3 = (_Float16*)alloc((size_t)NPAD * 128 * 2);
  _Float16* WT = (_Float16*)alloc(86016 * 2);
  int* counts    = (int*)alloc((size_t)N * 4);
  int* offsets   = (int*)alloc((size_t)(N + 1) * 4);
  int* fillpos   = (int*)alloc((size_t)N * 4);
  float* deginv  = (float*)alloc((size_t)N * 4);
  int* blockSums = (int*)alloc(1024 * 4);
  int* esrc      = (int*)alloc((size_t)E * 4);
  unsigned* gkey = (unsigned*)alloc(16 * 64 * 4);
  float* gsum    = (float*)alloc(16 * 64 * 4);
  int* gcnt      = (int*)alloc(16 * 4);
  float* OPT     = (float*)alloc(120 * 128 * 4);
  float* TYTb    = (float*)alloc(8 * 128 * 4);
  (void)ws_size; (void)n_in; (void)out_size;

  _Float16* WTenc = WT + 0;       // 128 x 160 (table-decomposed encode weight)
  _Float16* WTp0  = WT + 28672;   // 128 x 128
  _Float16* WTl0  = WT + 45056;   // 64 x 128
  _Float16* WTr0  = WT + 53248;   // 64 x 128
  _Float16* WTp1  = WT + 61440;   // 64 x 64
  _Float16* WTl1  = WT + 65536;
  _Float16* WTr1  = WT + 69632;
  _Float16* WTp2  = WT + 73728;
  _Float16* WTl2  = WT + 77824;
  _Float16* WTr2  = WT + 81920;

  WDs wds;
  wds.d[0] = {lin_w, WTenc, 0, 0, 1, 0};  // zero-size: encode weight built by k_wenc2
  wds.d[1] = {wp[0], WTp0, 128, 128, 128, 28672};
  wds.d[2] = {wl[0], WTl0, 128, 64, 128, 45056};
  wds.d[3] = {wr[0], WTr0, 128, 64, 128, 53248};
  wds.d[4] = {wp[1], WTp1, 64, 64, 64, 61440};
  wds.d[5] = {wl[1], WTl1, 64, 64, 64, 65536};
  wds.d[6] = {wr[1], WTr1, 64, 64, 64, 69632};
  wds.d[7] = {wp[2], WTp2, 64, 64, 64, 73728};
  wds.d[8] = {wl[2], WTl2, 64, 64, 64, 77824};
  wds.d[9] = {wr[2], WTr2, 64, 64, 64, 81920};
  wds.total = 86016;

  hipMemsetAsync(counts, 0, (size_t)N * 4, stream);
  hipMemsetAsync(gkey, 0, 16 * 64 * 4, stream);
  hipMemsetAsync(gsum, 0, 16 * 64 * 4, stream);
  hipMemsetAsync(gcnt, 0, 16 * 4, stream);
  // Zero the never-stored tail rows [N, NPAD) of the activation buffers so every
  // byte any kernel reads is written in-launch -> output is call-invariant under
  // graph replay / workspace re-poisoning (k_mm A-loads cover NPAD rows; stores
  // are guarded r < N). 48 KiB each — negligible.
  if (NPAD > N) {
    const size_t tail = (size_t)(NPAD - N) * 128 * 2;
    hipMemsetAsync(X1 + (size_t)N * 128, 0, tail, stream);
    hipMemsetAsync(R2 + (size_t)N * 128, 0, tail, stream);
    hipMemsetAsync(R3 + (size_t)N * 128, 0, tail, stream);
  }

  const int nbE = (E + 255) / 256;
  const int nbN = (N + 255) / 256;
  const int nbMM = NPAD / 256;
  const int nbMMF = NPAD / 64;
  const int nbA128 = ((size_t)N * 32 + 255) / 256;
  const int nbA64  = ((size_t)N * 16 + 255) / 256;
  const int nbP = ((N + 63) / 64 + 3) / 4;

  k_wconv<<<(86016 + 255) / 256, 256, 0, stream>>>(wds);
  k_wenc2<<<(128 * 160 + 255) / 256, 256, 0, stream>>>(lin_w, WTenc);
  k_tab<<<(120 * 128 + 8 * 128 + 255) / 256, 256, 0, stream>>>(lin_w, lin_b, op_emb,
                                                               type_emb, OPT, TYTb);
  k_count<<<nbE, 256, 0, stream>>>(e_dst, counts, E);
  k_scan1<<<nbN, 256, 0, stream>>>(counts, offsets, blockSums, N);
  k_scan2<<<1, 1024, 0, stream>>>(blockSums, nbN);
  k_scan3<<<nbN, 256, 0, stream>>>(counts, offsets, blockSums, fillpos, deginv, N, E);
  k_fill<<<nbE, 256, 0, stream>>>(e_src, e_dst, fillpos, esrc, E);

  // fused encode (table-decomposed, all-LDS steady state) -> X1
  k_mmF<<<nbMMF, 256, 0, stream>>>(node_feat, cfgf, opcode, OPT, TYTb, WTenc, X1, N);

  // ---- layer 0 ----
  k_mm<128, 0, 128, 0><<<nbMM, 256, 0, stream>>>(X1, WTp0, nullptr, nullptr, bp[0], R2, N);
  k_agg<128><<<nbA128, 256, 0, stream>>>(R2, offsets, esrc, deginv, R3, N);
  k_mm<128, 128, 64, 1><<<nbMM, 256, 0, stream>>>(R3, WTl0, X1, WTr0, bl[0], R2, N);
  // ---- layer 1 ----
  k_mm<64, 0, 64, 0><<<nbMM, 256, 0, stream>>>(R2, WTp1, nullptr, nullptr, bp[1], R3, N);
  k_agg<64><<<nbA64, 256, 0, stream>>>(R3, offsets, esrc, deginv, X1, N);
  k_mm<64, 64, 64, 1><<<nbMM, 256, 0, stream>>>(X1, WTl1, R2, WTr1, bl[1], R3, N);
  // ---- layer 2 ----
  k_mm<64, 0, 64, 0><<<nbMM, 256, 0, stream>>>(R3, WTp2, nullptr, nullptr, bp[2], X1, N);
  k_agg<64><<<nbA64, 256, 0, stream>>>(X1, offsets, esrc, deginv, R2, N);
  k_mm<64, 64, 64, 1><<<nbMM, 256, 0, stream>>>(R2, WTl2, R3, WTr2, bl[2], X1, N);

  // pooling -> out (B=16)
  k_pool1<<<nbP, 256, 0, stream>>>(X1, batch, gkey, gsum, gcnt, N);
  k_pool2<<<1, 1024, 0, stream>>>(gkey, gsum, gcnt, post_w, post_b, (float*)d_out);
}